// Round 2
// baseline (1057.613 us; speedup 1.0000x reference)
//
#include <hip/hip_runtime.h>

#define MDIM 8192
#define KDIM 32
#define JT 256            // j-tile per LDS stage (= blockDim)
#define SROW 260          // LDS row stride in floats (16B-aligned, conflict-free)
#define TILES (MDIM / JT) // 32
#define RPW 4             // rows per wave
#define ROWS_PER_BLOCK 16 // 4 waves * 4 rows
#define NBLOCKS (MDIM / ROWS_PER_BLOCK) // 512

// waves_per_eu(2,2): pin allocator to 2 waves/EU so it may use up to 256 VGPR.
// R1 post-mortem: with only launch_bounds(256,2) the allocator picked 128 VGPR
// and spilled ~70 regs -> 2.3 GB scratch traffic -> 802 us. Live set is ~210.
__global__ __launch_bounds__(256) __attribute__((amdgpu_waves_per_eu(2, 2)))
void spectral_main(const float* __restrict__ W, const float* __restrict__ Y,
                   float* __restrict__ ws) {
    __shared__ float YT[KDIM * SROW];  // 33,280 B, transposed Y tile: YT[k][j_local]

    const int tid  = threadIdx.x;
    const int wave = tid >> 6;
    const int lane = tid & 63;
    const int rowBase = blockIdx.x * ROWS_PER_BLOCK + wave * RPW;
    const int jl = 4 * lane;           // lane's j offset within tile

    const float* W0 = W + (size_t)rowBase * MDIM;  // row t is W0 + t*MDIM

    float acc[RPW][KDIM];
#pragma unroll
    for (int t = 0; t < RPW; ++t)
#pragma unroll
        for (int k = 0; k < KDIM; ++k) acc[t][k] = 0.f;
    float accd[RPW] = {0.f, 0.f, 0.f, 0.f};

    // Staging registers: thread stages global row j = tile*JT + tid (32 floats)
    const float4* Yv = (const float4*)Y;   // Y[j][4q] -> Yv[j*8 + q]
    float4 yreg[8];
#pragma unroll
    for (int q = 0; q < 8; ++q) yreg[q] = Yv[(size_t)tid * 8 + q];

    float4 wcur[RPW], wnext[RPW];
#pragma unroll
    for (int t = 0; t < RPW; ++t)
        wcur[t] = *(const float4*)(W0 + (size_t)t * MDIM + jl);

    for (int tile = 0; tile < TILES; ++tile) {
        __syncthreads();   // previous compute done reading LDS
        // transpose-write staged tile: YT[k][tid] = Y[tile*JT + tid][k]
#pragma unroll
        for (int q = 0; q < 8; ++q) {
            YT[(4 * q + 0) * SROW + tid] = yreg[q].x;
            YT[(4 * q + 1) * SROW + tid] = yreg[q].y;
            YT[(4 * q + 2) * SROW + tid] = yreg[q].z;
            YT[(4 * q + 3) * SROW + tid] = yreg[q].w;
        }
        __syncthreads();   // YT visible

        // Prefetch next tile (consumed after the next barrier pair -> latency hidden)
        if (tile + 1 < TILES) {
#pragma unroll
            for (int q = 0; q < 8; ++q)
                yreg[q] = Yv[(size_t)((tile + 1) * JT + tid) * 8 + q];
            const size_t joff = (size_t)(tile + 1) * JT + jl;
#pragma unroll
            for (int t = 0; t < RPW; ++t)
                wnext[t] = *(const float4*)(W0 + (size_t)t * MDIM + joff);
        }

        // Compute: 32 ds_read_b128 + 512 FMA per lane
#pragma unroll
        for (int k = 0; k < KDIM; ++k) {
            float4 y4 = *(const float4*)&YT[k * SROW + jl];
#pragma unroll
            for (int t = 0; t < RPW; ++t) {
                acc[t][k] += wcur[t].x * y4.x;
                acc[t][k] += wcur[t].y * y4.y;
                acc[t][k] += wcur[t].z * y4.z;
                acc[t][k] += wcur[t].w * y4.w;
            }
        }
#pragma unroll
        for (int t = 0; t < RPW; ++t)
            accd[t] += (wcur[t].x + wcur[t].y) + (wcur[t].z + wcur[t].w);

        if (tile + 1 < TILES) {
#pragma unroll
            for (int t = 0; t < RPW; ++t) wcur[t] = wnext[t];
        }
    }

    // Epilogue: per row, s = Y_row . WY_row (linear in lane partials), d = row sum
    float contrib = 0.f;
#pragma unroll
    for (int t = 0; t < RPW; ++t) {
        const float* Yrow = Y + (size_t)(rowBase + t) * KDIM;
        float s = 0.f;
#pragma unroll
        for (int k = 0; k < KDIM; ++k) s += Yrow[k] * acc[t][k];
        float d = accd[t];
#pragma unroll
        for (int off = 32; off > 0; off >>= 1) {
            s += __shfl_xor(s, off);
            d += __shfl_xor(d, off);
        }
        float yy = 0.f;
#pragma unroll
        for (int k = 0; k < KDIM; ++k) yy += Yrow[k] * Yrow[k];
        contrib += yy - s / d;
    }
    if (lane == 0) atomicAdd(ws, contrib);
}

__global__ void zero_ws_kernel(float* ws) { ws[0] = 0.f; }

__global__ void finalize_kernel(const float* __restrict__ ws, float* __restrict__ out) {
    out[0] = ws[0] / (float)MDIM;
}

extern "C" void kernel_launch(void* const* d_in, const int* in_sizes, int n_in,
                              void* d_out, int out_size, void* d_ws, size_t ws_size,
                              hipStream_t stream) {
    const float* W = (const float*)d_in[0];
    const float* Y = (const float*)d_in[1];
    float* out = (float*)d_out;
    float* ws  = (float*)d_ws;

    zero_ws_kernel<<<1, 1, 0, stream>>>(ws);
    spectral_main<<<NBLOCKS, 256, 0, stream>>>(W, Y, ws);
    finalize_kernel<<<1, 1, 0, stream>>>(ws, out);
}

// Round 3
// 400.871 us; speedup vs baseline: 2.6383x; 2.6383x over previous
//
#include <hip/hip_runtime.h>

#define MDIM 8192
#define KDIM 32
#define JT 256            // j-tile per LDS stage (= blockDim)
#define SROW 260          // LDS row stride in floats (16B-aligned, odd*4 -> conflict-free)
#define TILES (MDIM / JT) // 32
#define RPW 4             // rows per wave
#define ROWS_PER_BLOCK 16 // 4 waves * 4 rows
#define NBLOCKS (MDIM / ROWS_PER_BLOCK) // 512
#define BUFSZ (KDIM * SROW)             // floats per YT buffer

// LDS sized at 2 buffers = 66,560 B deliberately: caps HW occupancy at
// 2 blocks/CU = 2 waves/EU, so the allocator's own occupancy math grants a
// 256-VGPR budget. (R1/R2: 33 KB LDS -> heuristic targeted 4 waves/EU ->
// 128 VGPR cap -> ~80 spilled regs -> 3 GB scratch traffic -> 800 us.)
__global__ __launch_bounds__(256) __attribute__((amdgpu_waves_per_eu(2, 2)))
void spectral_main(const float* __restrict__ W, const float* __restrict__ Y,
                   float* __restrict__ ws) {
    __shared__ float YT[2 * BUFSZ];  // double-buffered transposed Y tile: [k][j_local]

    const int tid  = threadIdx.x;
    const int wave = tid >> 6;
    const int lane = tid & 63;
    const int rowBase = blockIdx.x * ROWS_PER_BLOCK + wave * RPW;
    const int jl = 4 * lane;           // lane's j offset within tile

    const float* W0 = W + (size_t)rowBase * MDIM;  // row t is W0 + t*MDIM

    float acc[RPW][KDIM];
#pragma unroll
    for (int t = 0; t < RPW; ++t)
#pragma unroll
        for (int k = 0; k < KDIM; ++k) acc[t][k] = 0.f;
    float accd[RPW] = {0.f, 0.f, 0.f, 0.f};

    const float4* Yv = (const float4*)Y;   // Y[j][4q] -> Yv[j*8 + q]

    // Prologue: stage tile 0 into buf 0, prefetch tile 1 into yreg, W tile 0.
    float4 yreg[8];
#pragma unroll
    for (int q = 0; q < 8; ++q) yreg[q] = Yv[(size_t)tid * 8 + q];
#pragma unroll
    for (int q = 0; q < 8; ++q) {
        YT[(4 * q + 0) * SROW + tid] = yreg[q].x;
        YT[(4 * q + 1) * SROW + tid] = yreg[q].y;
        YT[(4 * q + 2) * SROW + tid] = yreg[q].z;
        YT[(4 * q + 3) * SROW + tid] = yreg[q].w;
    }
#pragma unroll
    for (int q = 0; q < 8; ++q) yreg[q] = Yv[(size_t)(JT + tid) * 8 + q];

    float4 wcur[RPW], wnext[RPW];
#pragma unroll
    for (int t = 0; t < RPW; ++t)
        wcur[t] = *(const float4*)(W0 + (size_t)t * MDIM + jl);

    int p = 0;
    for (int tile = 0; tile < TILES; ++tile) {
        __syncthreads();   // buf p (staged last iter) visible; prev compute on buf p^1 done

        // Stage tile+1 (held in yreg) into the other buffer
        if (tile + 1 < TILES) {
            float* B = &YT[(p ^ 1) * BUFSZ];
#pragma unroll
            for (int q = 0; q < 8; ++q) {
                B[(4 * q + 0) * SROW + tid] = yreg[q].x;
                B[(4 * q + 1) * SROW + tid] = yreg[q].y;
                B[(4 * q + 2) * SROW + tid] = yreg[q].z;
                B[(4 * q + 3) * SROW + tid] = yreg[q].w;
            }
        }
        // Prefetch tile+2 Y and tile+1 W (land during this tile's compute)
        if (tile + 2 < TILES) {
#pragma unroll
            for (int q = 0; q < 8; ++q)
                yreg[q] = Yv[(size_t)((tile + 2) * JT + tid) * 8 + q];
        }
        if (tile + 1 < TILES) {
            const size_t joff = (size_t)(tile + 1) * JT + jl;
#pragma unroll
            for (int t = 0; t < RPW; ++t)
                wnext[t] = *(const float4*)(W0 + (size_t)t * MDIM + joff);
        }

        // Compute on buf p: 32 ds_read_b128 + 512 FMA per lane
        const float* Bc = &YT[p * BUFSZ];
#pragma unroll
        for (int k = 0; k < KDIM; ++k) {
            float4 y4 = *(const float4*)&Bc[k * SROW + jl];
#pragma unroll
            for (int t = 0; t < RPW; ++t) {
                acc[t][k] += wcur[t].x * y4.x;
                acc[t][k] += wcur[t].y * y4.y;
                acc[t][k] += wcur[t].z * y4.z;
                acc[t][k] += wcur[t].w * y4.w;
            }
        }
#pragma unroll
        for (int t = 0; t < RPW; ++t)
            accd[t] += (wcur[t].x + wcur[t].y) + (wcur[t].z + wcur[t].w);

        if (tile + 1 < TILES) {
#pragma unroll
            for (int t = 0; t < RPW; ++t) wcur[t] = wnext[t];
        }
        p ^= 1;
    }

    // Epilogue: per row, s = Y_row . WY_row (linear in lane partials), d = row sum
    float contrib = 0.f;
#pragma unroll
    for (int t = 0; t < RPW; ++t) {
        const float* Yrow = Y + (size_t)(rowBase + t) * KDIM;
        float s = 0.f;
#pragma unroll
        for (int k = 0; k < KDIM; ++k) s += Yrow[k] * acc[t][k];
        float d = accd[t];
#pragma unroll
        for (int off = 32; off > 0; off >>= 1) {
            s += __shfl_xor(s, off);
            d += __shfl_xor(d, off);
        }
        float yy = 0.f;
#pragma unroll
        for (int k = 0; k < KDIM; ++k) yy += Yrow[k] * Yrow[k];
        contrib += yy - s / d;
    }
    if (lane == 0) atomicAdd(ws, contrib);
}

__global__ void zero_ws_kernel(float* ws) { ws[0] = 0.f; }

__global__ void finalize_kernel(const float* __restrict__ ws, float* __restrict__ out) {
    out[0] = ws[0] / (float)MDIM;
}

extern "C" void kernel_launch(void* const* d_in, const int* in_sizes, int n_in,
                              void* d_out, int out_size, void* d_ws, size_t ws_size,
                              hipStream_t stream) {
    const float* W = (const float*)d_in[0];
    const float* Y = (const float*)d_in[1];
    float* out = (float*)d_out;
    float* ws  = (float*)d_ws;

    zero_ws_kernel<<<1, 1, 0, stream>>>(ws);
    spectral_main<<<NBLOCKS, 256, 0, stream>>>(W, Y, ws);
    finalize_kernel<<<1, 1, 0, stream>>>(ws, out);
}

// Round 4
// 384.306 us; speedup vs baseline: 2.7520x; 1.0431x over previous
//
#include <hip/hip_runtime.h>

#define MDIM 8192
#define KD 32            // Y columns
#define SROW 260         // LDS row stride (floats): 4-dword aligned, spreads banks
#define TILES_PB 4       // 256-j tiles per block (block owns 1024 j)
#define NBLOCKS 1024     // 128 row-groups x 8 j-splits
#define NRED 32          // blocks for zero/finalize (32*256 = 8192 rows)

typedef __attribute__((ext_vector_type(8))) short short8;
typedef __attribute__((ext_vector_type(4))) float f32x4;

// fp32 -> bf16 bits, round-to-nearest-even (inputs are finite; no NaN handling)
__device__ __forceinline__ short f2bf(float f) {
    unsigned int u = __builtin_bit_cast(unsigned int, f);
    u = (u + 0x7FFFu + ((u >> 16) & 1u)) >> 16;
    return (short)(unsigned short)u;
}

// Main: per-wave 16 rows, D[m][n] += W[m][j-chunk] * Y[j-chunk][n] via
// mfma_f32_16x16x32_bf16. A: m=lane&15, k=(lane>>4)*8+i. B: n=lane&15, same k.
// C/D: col=lane&15, row=(lane>>4)*4+reg (m89-verified).
__global__ __launch_bounds__(256)
void spectral_mfma(const float* __restrict__ W, const float* __restrict__ Y,
                   float* __restrict__ ws_s, float* __restrict__ ws_d) {
    __shared__ float YT[KD * SROW];   // fp32 transposed Y tile: YT[k][j_local]

    const int tid  = threadIdx.x;
    const int wave = tid >> 6;
    const int lane = tid & 63;
    const int g    = lane >> 4;       // k-chunk group 0..3
    const int n    = lane & 15;       // A: row-in-tile / B: col / D: col

    const int rg = blockIdx.x >> 3;   // row group 0..127 (64 rows)
    const int js = blockIdx.x & 7;    // j split 0..7 (1024 j each)
    const int rowBaseW = rg * 64 + wave * 16;
    const int rowW = rowBaseW + n;                 // this lane's A row
    const float* Wrow = W + (size_t)rowW * MDIM;
    const int jbase0 = js * 1024;

    f32x4 acc1 = {0.f, 0.f, 0.f, 0.f};   // cols 0..15
    f32x4 acc2 = {0.f, 0.f, 0.f, 0.f};   // cols 16..31
    float dpart = 0.f;                    // row-sum partial (exact fp32 W)

    for (int tile = 0; tile < TILES_PB; ++tile) {
        const int jt = jbase0 + tile * 256;

        __syncthreads();   // previous tile's LDS reads done

        // Stage Y tile transposed (R3-proven pattern): thread stages row jt+tid
        float4 yr[8];
        {
            const float4* yp = (const float4*)(Y + (size_t)(jt + tid) * KD);
#pragma unroll
            for (int q = 0; q < 8; ++q) yr[q] = yp[q];
        }
        // W loads for the whole tile issued while Y staging completes
        float4 wv[8][2];
#pragma unroll
        for (int jc = 0; jc < 8; ++jc) {
            const float* p = Wrow + jt + jc * 32 + g * 8;
            wv[jc][0] = *(const float4*)p;
            wv[jc][1] = *(const float4*)(p + 4);
        }
#pragma unroll
        for (int q = 0; q < 8; ++q) {
            YT[(4 * q + 0) * SROW + tid] = yr[q].x;
            YT[(4 * q + 1) * SROW + tid] = yr[q].y;
            YT[(4 * q + 2) * SROW + tid] = yr[q].z;
            YT[(4 * q + 3) * SROW + tid] = yr[q].w;
        }
        __syncthreads();   // YT visible

#pragma unroll
        for (int jc = 0; jc < 8; ++jc) {
            // exact row-sum from fp32 W before conversion
            dpart += ((wv[jc][0].x + wv[jc][0].y) + (wv[jc][0].z + wv[jc][0].w))
                   + ((wv[jc][1].x + wv[jc][1].y) + (wv[jc][1].z + wv[jc][1].w));
            short8 a;
            a[0] = f2bf(wv[jc][0].x); a[1] = f2bf(wv[jc][0].y);
            a[2] = f2bf(wv[jc][0].z); a[3] = f2bf(wv[jc][0].w);
            a[4] = f2bf(wv[jc][1].x); a[5] = f2bf(wv[jc][1].y);
            a[6] = f2bf(wv[jc][1].z); a[7] = f2bf(wv[jc][1].w);

            // B frags: B[k][n] = Y[jt + jc*32 + k][n] = YT[n][jc*32 + k]
            const int jo = jc * 32 + g * 8;
            const float* b1p = &YT[n * SROW + jo];
            const float* b2p = &YT[(n + 16) * SROW + jo];
            float4 b1a = *(const float4*)b1p, b1b = *(const float4*)(b1p + 4);
            float4 b2a = *(const float4*)b2p, b2b = *(const float4*)(b2p + 4);
            short8 b1, b2;
            b1[0] = f2bf(b1a.x); b1[1] = f2bf(b1a.y); b1[2] = f2bf(b1a.z); b1[3] = f2bf(b1a.w);
            b1[4] = f2bf(b1b.x); b1[5] = f2bf(b1b.y); b1[6] = f2bf(b1b.z); b1[7] = f2bf(b1b.w);
            b2[0] = f2bf(b2a.x); b2[1] = f2bf(b2a.y); b2[2] = f2bf(b2a.z); b2[3] = f2bf(b2a.w);
            b2[4] = f2bf(b2b.x); b2[5] = f2bf(b2b.y); b2[6] = f2bf(b2b.z); b2[7] = f2bf(b2b.w);

            acc1 = __builtin_amdgcn_mfma_f32_16x16x32_bf16(a, b1, acc1, 0, 0, 0);
            acc2 = __builtin_amdgcn_mfma_f32_16x16x32_bf16(a, b2, acc2, 0, 0, 0);
        }
    }

    // Epilogue: s_m = sum_n Y[row_m][n] * D[m][n] ; d_m = row sum of W.
#pragma unroll
    for (int r = 0; r < 4; ++r) {
        const int m = g * 4 + r;
        const int grow = rowBaseW + m;
        float ps = acc1[r] * Y[(size_t)grow * KD + n]
                 + acc2[r] * Y[(size_t)grow * KD + 16 + n];
        ps += __shfl_xor(ps, 1);
        ps += __shfl_xor(ps, 2);
        ps += __shfl_xor(ps, 4);
        ps += __shfl_xor(ps, 8);
        if (n == 0) atomicAdd(&ws_s[grow], ps);
    }
    float dv = dpart;                 // lane holds partial for row rowBaseW+n, chunk g
    dv += __shfl_xor(dv, 16);
    dv += __shfl_xor(dv, 32);
    if (g == 0) atomicAdd(&ws_d[rowBaseW + n], dv);
}

__global__ void zero_ws_kernel(float* __restrict__ ws_s, float* __restrict__ ws_d,
                               float* __restrict__ out) {
    const int i = blockIdx.x * 256 + threadIdx.x;
    ws_s[i] = 0.f;
    ws_d[i] = 0.f;
    if (i == 0) out[0] = 0.f;
}

__global__ void finalize_kernel(const float* __restrict__ Y,
                                const float* __restrict__ ws_s,
                                const float* __restrict__ ws_d,
                                float* __restrict__ out) {
    __shared__ float red[256];
    const int tid = threadIdx.x;
    const int i = blockIdx.x * 256 + tid;
    const float4* yp = (const float4*)(Y + (size_t)i * KD);
    float yy = 0.f;
#pragma unroll
    for (int q = 0; q < 8; ++q) {
        float4 y = yp[q];
        yy += y.x * y.x + y.y * y.y + y.z * y.z + y.w * y.w;
    }
    red[tid] = yy - ws_s[i] / ws_d[i];
    __syncthreads();
#pragma unroll
    for (int s = 128; s > 0; s >>= 1) {
        if (tid < s) red[tid] += red[tid + s];
        __syncthreads();
    }
    if (tid == 0) atomicAdd(out, red[0] * (1.0f / (float)MDIM));
}

extern "C" void kernel_launch(void* const* d_in, const int* in_sizes, int n_in,
                              void* d_out, int out_size, void* d_ws, size_t ws_size,
                              hipStream_t stream) {
    const float* W = (const float*)d_in[0];
    const float* Y = (const float*)d_in[1];
    float* out  = (float*)d_out;
    float* ws_s = (float*)d_ws;
    float* ws_d = ws_s + MDIM;

    zero_ws_kernel<<<NRED, 256, 0, stream>>>(ws_s, ws_d, out);
    spectral_mfma<<<NBLOCKS, 256, 0, stream>>>(W, Y, ws_s, ws_d);
    finalize_kernel<<<NRED, 256, 0, stream>>>(Y, ws_s, ws_d, out);
}

// Round 5
// 361.586 us; speedup vs baseline: 2.9249x; 1.0628x over previous
//
#include <hip/hip_runtime.h>

#define MDIM 8192
#define KD 32
#define JSPLIT 16                    // j-splits per row-group
#define JWIN (MDIM / JSPLIT)         // 512 j per block -> 16 K-chunks
#define NBLOCKS (128 * JSPLIT)       // 128 row-groups (64 rows) x 16 j-splits
#define NRED 32                      // 32*256 = 8192 rows for prep/finalize

typedef __attribute__((ext_vector_type(8))) short short8;
typedef __attribute__((ext_vector_type(4))) float f32x4;

union S8U { short8 s; uint4 u; };

// fp32 -> bf16 RNE (used once, in prep)
__device__ __forceinline__ unsigned short f2bf_rne(float f) {
    unsigned int u = __builtin_bit_cast(unsigned int, f);
    u = (u + 0x7FFFu + ((u >> 16) & 1u)) >> 16;
    return (unsigned short)u;
}

// pack two fp32 into two bf16 (truncation) with one v_perm_b32:
// result = [lo.b2, lo.b3, hi.b2, hi.b3]
__device__ __forceinline__ unsigned pk(float lo, float hi) {
    return __builtin_amdgcn_perm(__builtin_bit_cast(unsigned, hi),
                                 __builtin_bit_cast(unsigned, lo), 0x07060302u);
}

// Prep: YT[n][j] = bf16(Y[j][n]) (coalesced: lane j writes consecutive 2B),
// zero ws_s/ws_d/out. Reads 1 MB, writes 0.6 MB -> a few us.
__global__ void prep_kernel(const float* __restrict__ Y, unsigned short* __restrict__ YT,
                            float* __restrict__ ws_s, float* __restrict__ ws_d,
                            float* __restrict__ out) {
    const int j = blockIdx.x * 256 + threadIdx.x;
    ws_s[j] = 0.f;
    ws_d[j] = 0.f;
    if (j == 0) out[0] = 0.f;
    const float4* yp = (const float4*)(Y + (size_t)j * KD);
#pragma unroll
    for (int q = 0; q < 8; ++q) {
        float4 v = yp[q];
        YT[(size_t)(4 * q + 0) * MDIM + j] = f2bf_rne(v.x);
        YT[(size_t)(4 * q + 1) * MDIM + j] = f2bf_rne(v.y);
        YT[(size_t)(4 * q + 2) * MDIM + j] = f2bf_rne(v.z);
        YT[(size_t)(4 * q + 3) * MDIM + j] = f2bf_rne(v.w);
    }
}

// Main: barrier-free streaming GEMM. Wave owns 16 rows; per 32-j chunk:
// A = W (fp32 loads + perm-pack to bf16), B = YT (direct 16B bf16 loads),
// 3 MFMAs (cols 0-15, cols 16-31, ones -> row sums).
// mfma_f32_16x16x32_bf16: A m=lane&15, k=(lane>>4)*8+i; D col=lane&15,
// row=(lane>>4)*4+reg (m89-verified, R4-passed).
__global__ __launch_bounds__(256)
void spectral_mfma(const float* __restrict__ W, const unsigned short* __restrict__ YTb,
                   const float* __restrict__ Y,
                   float* __restrict__ ws_s, float* __restrict__ ws_d) {
    const int tid  = threadIdx.x;
    const int wave = tid >> 6;
    const int lane = tid & 63;
    const int g    = lane >> 4;      // k-chunk group 0..3
    const int n    = lane & 15;      // A row-in-tile / B col / D col

    const int rg = blockIdx.x >> 4;            // row group 0..127
    const int js = blockIdx.x & (JSPLIT - 1);  // j split 0..15
    const int rowBase = rg * 64 + wave * 16;
    const float* Wrow = W + (size_t)(rowBase + n) * MDIM;
    const int j0 = js * JWIN;

    f32x4 acc1 = {0.f, 0.f, 0.f, 0.f};   // cols 0..15
    f32x4 acc2 = {0.f, 0.f, 0.f, 0.f};   // cols 16..31
    f32x4 acc3 = {0.f, 0.f, 0.f, 0.f};   // row sums (B = ones)

    S8U ones;
    ones.u = make_uint4(0x3F803F80u, 0x3F803F80u, 0x3F803F80u, 0x3F803F80u);

    const float* wp0 = Wrow + j0 + g * 8;
    const unsigned short* bp0 = YTb + (size_t)n * MDIM + j0 + g * 8;

#pragma unroll 4
    for (int it = 0; it < JWIN / 32; ++it) {
        const float* wp = wp0 + it * 32;
        float4 w0 = *(const float4*)wp;
        float4 w1 = *(const float4*)(wp + 4);
        const unsigned short* bp = bp0 + it * 32;
        short8 b1 = *(const short8*)bp;
        short8 b2 = *(const short8*)(bp + (size_t)16 * MDIM);

        S8U a;
        a.u.x = pk(w0.x, w0.y);
        a.u.y = pk(w0.z, w0.w);
        a.u.z = pk(w1.x, w1.y);
        a.u.w = pk(w1.z, w1.w);

        acc1 = __builtin_amdgcn_mfma_f32_16x16x32_bf16(a.s, b1, acc1, 0, 0, 0);
        acc2 = __builtin_amdgcn_mfma_f32_16x16x32_bf16(a.s, b2, acc2, 0, 0, 0);
        acc3 = __builtin_amdgcn_mfma_f32_16x16x32_bf16(a.s, ones.s, acc3, 0, 0, 0);
    }

    // Epilogue: s_m = sum_n Y[m][n]*D[m][n]; d_m = acc3 row sum (same in all cols)
#pragma unroll
    for (int r = 0; r < 4; ++r) {
        const int grow = rowBase + g * 4 + r;
        float ps = acc1[r] * Y[(size_t)grow * KD + n]
                 + acc2[r] * Y[(size_t)grow * KD + 16 + n];
        ps += __shfl_xor(ps, 1);
        ps += __shfl_xor(ps, 2);
        ps += __shfl_xor(ps, 4);
        ps += __shfl_xor(ps, 8);
        if (n == 0) {
            atomicAdd(&ws_s[grow], ps);
            atomicAdd(&ws_d[grow], acc3[r]);
        }
    }
}

__global__ void finalize_kernel(const float* __restrict__ Y,
                                const float* __restrict__ ws_s,
                                const float* __restrict__ ws_d,
                                float* __restrict__ out) {
    __shared__ float red[256];
    const int tid = threadIdx.x;
    const int i = blockIdx.x * 256 + tid;
    const float4* yp = (const float4*)(Y + (size_t)i * KD);
    float yy = 0.f;
#pragma unroll
    for (int q = 0; q < 8; ++q) {
        float4 y = yp[q];
        yy += y.x * y.x + y.y * y.y + y.z * y.z + y.w * y.w;
    }
    red[tid] = yy - ws_s[i] / ws_d[i];
    __syncthreads();
#pragma unroll
    for (int s = 128; s > 0; s >>= 1) {
        if (tid < s) red[tid] += red[tid + s];
        __syncthreads();
    }
    if (tid == 0) atomicAdd(out, red[0] * (1.0f / (float)MDIM));
}

extern "C" void kernel_launch(void* const* d_in, const int* in_sizes, int n_in,
                              void* d_out, int out_size, void* d_ws, size_t ws_size,
                              hipStream_t stream) {
    const float* W = (const float*)d_in[0];
    const float* Y = (const float*)d_in[1];
    float* out  = (float*)d_out;
    float* ws_s = (float*)d_ws;
    float* ws_d = ws_s + MDIM;
    unsigned short* YTb = (unsigned short*)(ws_s + 2 * MDIM);

    prep_kernel<<<NRED, 256, 0, stream>>>(Y, YTb, ws_s, ws_d, out);
    spectral_mfma<<<NBLOCKS, 256, 0, stream>>>(W, YTb, Y, ws_s, ws_d);
    finalize_kernel<<<NRED, 256, 0, stream>>>(Y, ws_s, ws_d, out);
}